// Round 2
// baseline (678.248 us; speedup 1.0000x reference)
//
#include <hip/hip_runtime.h>
#include <hip/hip_bf16.h>

typedef __attribute__((ext_vector_type(8))) short bf16x8;
typedef __attribute__((ext_vector_type(8))) unsigned short ushort8;
typedef __attribute__((ext_vector_type(4))) float f32x4;
typedef unsigned int u32;

#define D_DIM 512
#define C_DIM 1024

__device__ __forceinline__ unsigned short f2bf(float x) {
  u32 u = __float_as_uint(x);
  u32 r = (u + 0x7fffu + ((u >> 16) & 1u)) >> 16;
  return (unsigned short)r;
}

// Normalize rows of length 512 (l2, +1e-12 eps) and cast to bf16.
__global__ __launch_bounds__(256) void rownorm_kernel(
    const float* __restrict__ src, unsigned short* __restrict__ dst) {
  int row = blockIdx.x * 4 + (threadIdx.x >> 6);
  int lane = threadIdx.x & 63;
  const float* s = src + (size_t)row * D_DIM + lane * 8;
  float4 v0 = *(const float4*)s;
  float4 v1 = *(const float4*)(s + 4);
  float ss = v0.x * v0.x + v0.y * v0.y + v0.z * v0.z + v0.w * v0.w +
             v1.x * v1.x + v1.y * v1.y + v1.z * v1.z + v1.w * v1.w;
#pragma unroll
  for (int m = 32; m >= 1; m >>= 1) ss += __shfl_xor(ss, m);
  float rinv = rsqrtf(ss + 1e-12f);
  float tv[8] = {v0.x, v0.y, v0.z, v0.w, v1.x, v1.y, v1.z, v1.w};
  ushort8 o;
#pragma unroll
  for (int i = 0; i < 8; ++i) o[i] = f2bf(tv[i] * rinv);
  *(ushort8*)(dst + (size_t)row * D_DIM + lane * 8) = o;
}

// vbT[n][k] = bf16(val[k][n])  (transpose+cast, 32x32 LDS tiles)
__global__ __launch_bounds__(256) void valT_kernel(
    const float* __restrict__ val, unsigned short* __restrict__ vbT) {
  __shared__ float tile[32][33];
  int bx = blockIdx.x & 31;  // n tile
  int by = blockIdx.x >> 5;  // k tile
  int t = threadIdx.x;
  int r = t >> 5, c = t & 31;
#pragma unroll
  for (int i = 0; i < 4; ++i)
    tile[r + i * 8][c] = val[(size_t)(by * 32 + r + i * 8) * C_DIM + bx * 32 + c];
  __syncthreads();
#pragma unroll
  for (int i = 0; i < 4; ++i)
    vbT[(size_t)(bx * 32 + r + i * 8) * C_DIM + by * 32 + c] = f2bf(tile[c][r + i * 8]);
}

// Fused: per block 64 q-rows, full 1024 out cols. 8 waves, 512 threads.
// For each 128-wide c-tile: G1 sim=qs@kb^T (LDS+L2), sharp->ws LDS (swizzled),
// rowsum in regs; barrier; G2 acc += ws @ vbT (vbT B-frags direct from L2).
// Epilogue: reduce rowsums via LDS, scale acc by 1/rsum, store f32.
__global__ __launch_bounds__(512, 2) void fused_kernel(
    const unsigned short* __restrict__ qb, const unsigned short* __restrict__ kb,
    const unsigned short* __restrict__ vbT, float* __restrict__ out) {
  __shared__ unsigned short qs[64 * 512];      // 64 KB, XOR-swizzled rows
  __shared__ unsigned short wsb[2][64 * 128];  // 2 x 16 KB, XOR-swizzled
  const int t = threadIdx.x;
  const int lane = t & 63;
  const int wv = t >> 6;  // 0..7
  const int lo = lane & 15, hi = lane >> 4;
  const int m0 = blockIdx.x * 64;

  // stage qs (reg-staged so we can swizzle the LDS write)
#pragma unroll
  for (int i = 0; i < 8; ++i) {
    int e = (i * 512 + t) * 8;
    int row = e >> 9, col = e & 511;
    ushort8 v = *(const ushort8*)(qb + (size_t)(m0 + row) * D_DIM + col);
    *(ushort8*)&qs[row * 512 + (col ^ ((row & 7) << 3))] = v;
  }

  f32x4 acc[4][8];
#pragma unroll
  for (int mi = 0; mi < 4; ++mi)
#pragma unroll
    for (int ni = 0; ni < 8; ++ni) acc[mi][ni] = (f32x4){0.f, 0.f, 0.f, 0.f};
  float rp[2][4];
#pragma unroll
  for (int mi = 0; mi < 2; ++mi)
#pragma unroll
    for (int jj = 0; jj < 4; ++jj) rp[mi][jj] = 0.f;

  const int wm = (wv >> 2) * 32;   // G1 wave row offset (0 or 32)
  const int wnc = (wv & 3) * 32;   // G1 wave col offset within c-tile

  __syncthreads();

  for (int ct = 0; ct < 8; ++ct) {
    const int cur = ct & 1;
    // ---- G1: sim(64x128) = qs @ kb[c-tile]^T
    f32x4 sa[2][2];
#pragma unroll
    for (int mi = 0; mi < 2; ++mi)
#pragma unroll
      for (int ni = 0; ni < 2; ++ni) sa[mi][ni] = (f32x4){0.f, 0.f, 0.f, 0.f};
#pragma unroll 4
    for (int ks = 0; ks < 16; ++ks) {
      int kg = ks * 32 + hi * 8;
      bf16x8 a[2], b[2];
#pragma unroll
      for (int mi = 0; mi < 2; ++mi) {
        int r = wm + mi * 16 + lo;
        a[mi] = *(const bf16x8*)&qs[r * 512 + (kg ^ ((r & 7) << 3))];
      }
#pragma unroll
      for (int ni = 0; ni < 2; ++ni) {
        int c = ct * 128 + wnc + ni * 16 + lo;
        b[ni] = *(const bf16x8*)&kb[(size_t)c * D_DIM + kg];
      }
#pragma unroll
      for (int mi = 0; mi < 2; ++mi)
#pragma unroll
        for (int ni = 0; ni < 2; ++ni)
          sa[mi][ni] = __builtin_amdgcn_mfma_f32_16x16x32_bf16(a[mi], b[ni], sa[mi][ni], 0, 0, 0);
    }
    // ---- sharp, rowsum (regs), write w-tile to LDS (swizzled)
#pragma unroll
    for (int mi = 0; mi < 2; ++mi)
#pragma unroll
      for (int jj = 0; jj < 4; ++jj) {
        int r = wm + mi * 16 + hi * 4 + jj;
        float vsum = 0.f;
#pragma unroll
        for (int ni = 0; ni < 2; ++ni) {
          float x = sa[mi][ni][jj];
          float s = 1.f / (1.f + __expf(5.f - 10.f * x)) +
                    1.f / (1.f + __expf(5.f + 10.f * x));
          vsum += s;
          int c = wnc + ni * 16 + lo;
          wsb[cur][r * 128 + (c ^ ((r & 7) << 3))] = f2bf(s);
        }
        vsum += __shfl_xor(vsum, 1);
        vsum += __shfl_xor(vsum, 2);
        vsum += __shfl_xor(vsum, 4);
        vsum += __shfl_xor(vsum, 8);
        rp[mi][jj] += vsum;
      }
    __syncthreads();
    // ---- G2: acc(64 x 128-per-wave) += w(64x128) @ vbT[:, c-tile]^T
#pragma unroll
    for (int kk = 0; kk < 4; ++kk) {
      int kg = kk * 32 + hi * 8;
      bf16x8 a[4], b[8];
#pragma unroll
      for (int mi = 0; mi < 4; ++mi) {
        int r = mi * 16 + lo;
        a[mi] = *(const bf16x8*)&wsb[cur][r * 128 + (kg ^ ((r & 7) << 3))];
      }
#pragma unroll
      for (int ni = 0; ni < 8; ++ni) {
        int n = wv * 128 + ni * 16 + lo;
        b[ni] = *(const bf16x8*)&vbT[(size_t)n * C_DIM + ct * 128 + kg];
      }
#pragma unroll
      for (int mi = 0; mi < 4; ++mi)
#pragma unroll
        for (int ni = 0; ni < 8; ++ni)
          acc[mi][ni] = __builtin_amdgcn_mfma_f32_16x16x32_bf16(a[mi], b[ni], acc[mi][ni], 0, 0, 0);
    }
    // no trailing barrier: next G1 writes the OTHER ws buffer; the next
    // iteration's mid barrier protects the buffer we just read.
  }

  // ---- epilogue: rowsum reduce + scale + store
  __syncthreads();  // all G2 reads of wsb done
  float* rsf = (float*)&wsb[0][0];
  if (t < 64) rsf[t] = 0.f;
  __syncthreads();
  if (lo == 0) {
#pragma unroll
    for (int mi = 0; mi < 2; ++mi)
#pragma unroll
      for (int jj = 0; jj < 4; ++jj)
        atomicAdd(&rsf[wm + mi * 16 + hi * 4 + jj], rp[mi][jj]);
  }
  __syncthreads();
#pragma unroll
  for (int mi = 0; mi < 4; ++mi) {
    float rinv[4];
#pragma unroll
    for (int jj = 0; jj < 4; ++jj) rinv[jj] = 1.f / rsf[mi * 16 + hi * 4 + jj];
#pragma unroll
    for (int ni = 0; ni < 8; ++ni)
#pragma unroll
      for (int jj = 0; jj < 4; ++jj)
        out[(size_t)(m0 + mi * 16 + hi * 4 + jj) * C_DIM + wv * 128 + ni * 16 + lo] =
            acc[mi][ni][jj] * rinv[jj];
  }
}

extern "C" void kernel_launch(void* const* d_in, const int* in_sizes, int n_in,
                              void* d_out, int out_size, void* d_ws, size_t ws_size,
                              hipStream_t stream) {
  const float* query = (const float*)d_in[0];
  const float* key = (const float*)d_in[1];
  const float* val = (const float*)d_in[2];
  float* out = (float*)d_out;
  const int B = in_sizes[0] / D_DIM;  // 65536

  char* ws = (char*)d_ws;
  unsigned short* kb = (unsigned short*)(ws);                       // 1 MB
  unsigned short* vbT = (unsigned short*)(ws + (1ull << 20));       // 2 MB
  unsigned short* qb = (unsigned short*)(ws + 4ull * (1ull << 20)); // 64 MB

  rownorm_kernel<<<dim3(B / 4), dim3(256), 0, stream>>>(query, qb);
  rownorm_kernel<<<dim3(C_DIM / 4), dim3(256), 0, stream>>>(key, kb);
  valT_kernel<<<dim3(1024), dim3(256), 0, stream>>>(val, vbT);

  fused_kernel<<<dim3(B / 64), dim3(512), 0, stream>>>(qb, kb, vbT, out);
}

// Round 3
// 438.559 us; speedup vs baseline: 1.5465x; 1.5465x over previous
//
#include <hip/hip_runtime.h>
#include <hip/hip_bf16.h>

typedef __attribute__((ext_vector_type(8))) short bf16x8;
typedef __attribute__((ext_vector_type(8))) unsigned short ushort8;
typedef __attribute__((ext_vector_type(4))) float f32x4;
typedef unsigned int u32;

#define D_DIM 512
#define C_DIM 1024

__device__ __forceinline__ unsigned short f2bf(float x) {
  u32 u = __float_as_uint(x);
  u32 r = (u + 0x7fffu + ((u >> 16) & 1u)) >> 16;
  return (unsigned short)r;
}

__device__ __forceinline__ void async16(const void* g, void* l) {
  __builtin_amdgcn_global_load_lds(
      (const __attribute__((address_space(1))) u32*)g,
      (__attribute__((address_space(3))) u32*)l, 16, 0, 0);
}

// Normalize rows of length 512 (l2, +1e-12 eps) and cast to bf16.
__global__ __launch_bounds__(256) void rownorm_kernel(
    const float* __restrict__ src, unsigned short* __restrict__ dst) {
  int row = blockIdx.x * 4 + (threadIdx.x >> 6);
  int lane = threadIdx.x & 63;
  const float* s = src + (size_t)row * D_DIM + lane * 8;
  float4 v0 = *(const float4*)s;
  float4 v1 = *(const float4*)(s + 4);
  float ss = v0.x * v0.x + v0.y * v0.y + v0.z * v0.z + v0.w * v0.w +
             v1.x * v1.x + v1.y * v1.y + v1.z * v1.z + v1.w * v1.w;
#pragma unroll
  for (int m = 32; m >= 1; m >>= 1) ss += __shfl_xor(ss, m);
  float rinv = rsqrtf(ss + 1e-12f);
  float tv[8] = {v0.x, v0.y, v0.z, v0.w, v1.x, v1.y, v1.z, v1.w};
  ushort8 o;
#pragma unroll
  for (int i = 0; i < 8; ++i) o[i] = f2bf(tv[i] * rinv);
  *(ushort8*)(dst + (size_t)row * D_DIM + lane * 8) = o;
}

// vbT[n][k] = bf16(val[k][n])  (transpose+cast, 32x32 LDS tiles)
__global__ __launch_bounds__(256) void valT_kernel(
    const float* __restrict__ val, unsigned short* __restrict__ vbT) {
  __shared__ float tile[32][33];
  int bx = blockIdx.x & 31;  // n tile
  int by = blockIdx.x >> 5;  // k tile
  int t = threadIdx.x;
  int r = t >> 5, c = t & 31;
#pragma unroll
  for (int i = 0; i < 4; ++i)
    tile[r + i * 8][c] = val[(size_t)(by * 32 + r + i * 8) * C_DIM + bx * 32 + c];
  __syncthreads();
#pragma unroll
  for (int i = 0; i < 4; ++i)
    vbT[(size_t)(bx * 32 + r + i * 8) * C_DIM + by * 32 + c] = f2bf(tile[c][r + i * 8]);
}

// C = A(MxK bf16 rm) * B^T(NxK bf16 rm). 128x128 tile, BK=32, 4 waves 2x2,
// 4x4 16x16x32 MFMA per wave, double-buffered global_load_lds (m97 structure),
// XCD-chunked block swizzle (8 n-tiles of one m-tile -> same XCD's L2).
// SHARP: s=sig(10x-5)+sig(-10x-5); rowsum atomics; LDS-transpose coalesced
//        bf16 store of s.   !SHARP: scale by 1/rsum[row], scattered f32 store.
template <int K, bool SHARP>
__global__ __launch_bounds__(256) void gemm_kernel(
    const unsigned short* __restrict__ A, const unsigned short* __restrict__ Bm,
    unsigned short* __restrict__ wout, float* __restrict__ rsum,
    float* __restrict__ fout) {
  // A0 @ 0, B0 @ 4096, A1 @ 8192, B1 @ 12288 (u16 offsets); epilogue reuses all 32KB
  __shared__ unsigned short smem[16384];
  const int bid = blockIdx.x;
  // XCD-chunked bijective swizzle: nwg=4096, 8 XCDs, 512 blocks per XCD chunk.
  const int wg = (bid & 7) * 512 + (bid >> 3);
  const int m0 = (wg >> 3) * 128;  // 512 m-tiles
  const int n0 = (wg & 7) * 128;   // 8 n-tiles
  const int t = threadIdx.x;
  const int lane = t & 63;
  const int wv = t >> 6;
  const int wm = (wv >> 1) * 64;
  const int wn = (wv & 1) * 64;
  const int lo = lane & 15, hi = lane >> 4;

  f32x4 acc[4][4];
#pragma unroll
  for (int i = 0; i < 4; ++i)
#pragma unroll
    for (int j = 0; j < 4; ++j) acc[i][j] = (f32x4){0.f, 0.f, 0.f, 0.f};

  auto stage = [&](int buf, int k0) {
#pragma unroll
    for (int i = 0; i < 2; ++i) {
      int c = i * 256 + t;
      int row = c >> 2, cc = c & 3;
      async16(A + (size_t)(m0 + row) * K + k0 + cc * 8, &smem[buf * 8192 + c * 8]);
      async16(Bm + (size_t)(n0 + row) * K + k0 + cc * 8, &smem[buf * 8192 + 4096 + c * 8]);
    }
  };

  stage(0, 0);
  __syncthreads();
  const int NK = K / 32;
#pragma unroll 2
  for (int kt = 0; kt < NK; ++kt) {
    int cur = kt & 1;
    if (kt + 1 < NK) stage(cur ^ 1, (kt + 1) * 32);
    bf16x8 a[4], b[4];
    int kg = hi * 8;
#pragma unroll
    for (int i = 0; i < 4; ++i) {
      a[i] = *(const bf16x8*)&smem[cur * 8192 + (wm + i * 16 + lo) * 32 + kg];
      b[i] = *(const bf16x8*)&smem[cur * 8192 + 4096 + (wn + i * 16 + lo) * 32 + kg];
    }
#pragma unroll
    for (int i = 0; i < 4; ++i)
#pragma unroll
      for (int j = 0; j < 4; ++j)
        acc[i][j] = __builtin_amdgcn_mfma_f32_16x16x32_bf16(a[i], b[j], acc[i][j], 0, 0, 0);
    __syncthreads();
  }

  const int rbase = m0 + wm + (hi << 2);
  const int cbase = n0 + wn + lo;

  if (SHARP) {
    // sharp + per-row partial sums + scatter into LDS (tile-row-major u16)
    float rs[4][4];
#pragma unroll
    for (int i = 0; i < 4; ++i)
#pragma unroll
      for (int j = 0; j < 4; ++j) rs[i][j] = 0.f;
#pragma unroll
    for (int mi = 0; mi < 4; ++mi)
#pragma unroll
      for (int ni = 0; ni < 4; ++ni)
#pragma unroll
        for (int j = 0; j < 4; ++j) {
          float x = acc[mi][ni][j];
          float s = 1.f / (1.f + __expf(5.f - 10.f * x)) +
                    1.f / (1.f + __expf(5.f + 10.f * x));
          rs[mi][j] += s;
          int r = wm + mi * 16 + (hi << 2) + j;
          int c = wn + ni * 16 + lo;
          smem[r * 128 + c] = f2bf(s);
        }
#pragma unroll
    for (int mi = 0; mi < 4; ++mi)
#pragma unroll
      for (int j = 0; j < 4; ++j) {
        float v = rs[mi][j];
        v += __shfl_xor(v, 1);
        v += __shfl_xor(v, 2);
        v += __shfl_xor(v, 4);
        v += __shfl_xor(v, 8);
        if (lo == 0) atomicAdd(&rsum[rbase + mi * 16 + j], v);
      }
    __syncthreads();
    // coalesced 16B/lane store of the 128x128 tile
#pragma unroll
    for (int pass = 0; pass < 8; ++pass) {
      int idx = pass * 2048 + t * 8;
      int row = idx >> 7, col = idx & 127;
      ushort8 v = *(const ushort8*)&smem[idx];
      *(ushort8*)&wout[(size_t)(m0 + row) * C_DIM + n0 + col] = v;
    }
  } else {
    float rinv[4][4];
#pragma unroll
    for (int mi = 0; mi < 4; ++mi)
#pragma unroll
      for (int j = 0; j < 4; ++j)
        rinv[mi][j] = 1.f / rsum[rbase + mi * 16 + j];
#pragma unroll
    for (int mi = 0; mi < 4; ++mi)
#pragma unroll
      for (int ni = 0; ni < 4; ++ni)
#pragma unroll
        for (int j = 0; j < 4; ++j)
          fout[(size_t)(rbase + mi * 16 + j) * C_DIM + cbase + ni * 16] =
              acc[mi][ni][j] * rinv[mi][j];
  }
}

extern "C" void kernel_launch(void* const* d_in, const int* in_sizes, int n_in,
                              void* d_out, int out_size, void* d_ws, size_t ws_size,
                              hipStream_t stream) {
  const float* query = (const float*)d_in[0];
  const float* key = (const float*)d_in[1];
  const float* val = (const float*)d_in[2];
  float* out = (float*)d_out;
  const int B = in_sizes[0] / D_DIM;  // 65536

  char* ws = (char*)d_ws;
  unsigned short* kb = (unsigned short*)(ws);                         // 1 MB
  unsigned short* vbT = (unsigned short*)(ws + (1ull << 20));         // 2 MB
  float* rsum = (float*)(ws + 3ull * (1ull << 20));                   // 256 KB
  unsigned short* qb = (unsigned short*)(ws + 4ull * (1ull << 20));   // 64 MB
  unsigned short* wbf = (unsigned short*)(ws + 68ull * (1ull << 20)); // 128 MB

  rownorm_kernel<<<dim3(B / 4), dim3(256), 0, stream>>>(query, qb);
  rownorm_kernel<<<dim3(C_DIM / 4), dim3(256), 0, stream>>>(key, kb);
  valT_kernel<<<dim3(1024), dim3(256), 0, stream>>>(val, vbT);
  hipMemsetAsync(rsum, 0, (size_t)B * sizeof(float), stream);

  dim3 grid((B / 128) * (C_DIM / 128));
  gemm_kernel<D_DIM, true><<<grid, dim3(256), 0, stream>>>(qb, kb, wbf, rsum, nullptr);
  gemm_kernel<C_DIM, false><<<grid, dim3(256), 0, stream>>>(wbf, vbT, nullptr, rsum, out);
}

// Round 4
// 425.296 us; speedup vs baseline: 1.5948x; 1.0312x over previous
//
#include <hip/hip_runtime.h>
#include <hip/hip_bf16.h>

typedef __attribute__((ext_vector_type(8))) short bf16x8;
typedef __attribute__((ext_vector_type(8))) unsigned short ushort8;
typedef __attribute__((ext_vector_type(4))) float f32x4;
typedef unsigned int u32;

#define D_DIM 512
#define C_DIM 1024

__device__ __forceinline__ unsigned short f2bf(float x) {
  u32 u = __float_as_uint(x);
  u32 r = (u + 0x7fffu + ((u >> 16) & 1u)) >> 16;
  return (unsigned short)r;
}

__device__ __forceinline__ void async16(const void* g, void* l) {
  __builtin_amdgcn_global_load_lds(
      (const __attribute__((address_space(1))) u32*)g,
      (__attribute__((address_space(3))) u32*)l, 16, 0, 0);
}

// Normalize rows of length 512 (l2, +1e-12 eps) and cast to bf16.
__global__ __launch_bounds__(256) void rownorm_kernel(
    const float* __restrict__ src, unsigned short* __restrict__ dst) {
  int row = blockIdx.x * 4 + (threadIdx.x >> 6);
  int lane = threadIdx.x & 63;
  const float* s = src + (size_t)row * D_DIM + lane * 8;
  float4 v0 = *(const float4*)s;
  float4 v1 = *(const float4*)(s + 4);
  float ss = v0.x * v0.x + v0.y * v0.y + v0.z * v0.z + v0.w * v0.w +
             v1.x * v1.x + v1.y * v1.y + v1.z * v1.z + v1.w * v1.w;
#pragma unroll
  for (int m = 32; m >= 1; m >>= 1) ss += __shfl_xor(ss, m);
  float rinv = rsqrtf(ss + 1e-12f);
  float tv[8] = {v0.x, v0.y, v0.z, v0.w, v1.x, v1.y, v1.z, v1.w};
  ushort8 o;
#pragma unroll
  for (int i = 0; i < 8; ++i) o[i] = f2bf(tv[i] * rinv);
  *(ushort8*)(dst + (size_t)row * D_DIM + lane * 8) = o;
}

// vbT[n][k] = bf16(val[k][n])  (transpose+cast, 32x32 LDS tiles)
__global__ __launch_bounds__(256) void valT_kernel(
    const float* __restrict__ val, unsigned short* __restrict__ vbT) {
  __shared__ float tile[32][33];
  int bx = blockIdx.x & 31;  // n tile
  int by = blockIdx.x >> 5;  // k tile
  int t = threadIdx.x;
  int r = t >> 5, c = t & 31;
#pragma unroll
  for (int i = 0; i < 4; ++i)
    tile[r + i * 8][c] = val[(size_t)(by * 32 + r + i * 8) * C_DIM + bx * 32 + c];
  __syncthreads();
#pragma unroll
  for (int i = 0; i < 4; ++i)
    vbT[(size_t)(bx * 32 + r + i * 8) * C_DIM + by * 32 + c] = f2bf(tile[c][r + i * 8]);
}

// C = A(MxK bf16 rm) * B^T(NxK bf16 rm). 128x128 tile, BK=32, 4 waves 2x2,
// 4x4 16x16x32 MFMA per wave. Depth-2 counted-vmcnt pipeline: 4 circular LDS
// buffers; iter j waits vmcnt(4) (loads issued at j-2), raw s_barrier, issues
// stage(j+2), ds_reads buf j, MFMA under setprio. vmcnt never drains to 0 in
// the main loop (T3/T4); last iteration peeled with vmcnt(0).
// XCD-chunked block swizzle. SHARP epilogue: sigmoid-sharp + rowsum atomics +
// LDS-transpose coalesced bf16 store. !SHARP: scale by 1/rsum, f32 store.
template <int K, bool SHARP>
__global__ __launch_bounds__(256, 2) void gemm_kernel(
    const unsigned short* __restrict__ A, const unsigned short* __restrict__ Bm,
    unsigned short* __restrict__ wout, float* __restrict__ rsum,
    float* __restrict__ fout) {
  // 4 buffers x (A 8KB | B 8KB) = 64 KB; epilogue reuses first 32 KB.
  __shared__ unsigned short smem[4][8192];
  const int bid = blockIdx.x;
  // XCD-chunked bijective swizzle: nwg=4096, 8 XCDs, 512 blocks per chunk.
  const int wg = (bid & 7) * 512 + (bid >> 3);
  const int m0 = (wg >> 3) * 128;
  const int n0 = (wg & 7) * 128;
  const int t = threadIdx.x;
  const int lane = t & 63;
  const int wv = t >> 6;
  const int wm = (wv >> 1) * 64;
  const int wn = (wv & 1) * 64;
  const int lo = lane & 15, hi = lane >> 4;

  f32x4 acc[4][4];
#pragma unroll
  for (int i = 0; i < 4; ++i)
#pragma unroll
    for (int j = 0; j < 4; ++j) acc[i][j] = (f32x4){0.f, 0.f, 0.f, 0.f};

  auto stage = [&](int buf, int k0) {
#pragma unroll
    for (int i = 0; i < 2; ++i) {
      int c = i * 256 + t;  // 0..511 16B-slots
      int row = c >> 2, cc = c & 3;
      async16(A + (size_t)(m0 + row) * K + k0 + cc * 8, &smem[buf][c * 8]);
      async16(Bm + (size_t)(n0 + row) * K + k0 + cc * 8, &smem[buf][4096 + c * 8]);
    }
  };

  const int NK = K / 32;
  stage(0, 0);
  stage(1, 32);

  const int kg = hi * 8;
#pragma unroll 4
  for (int kt = 0; kt < NK - 1; ++kt) {
    const int cur = kt & 3;
    // wait for buf[kt] (issued at kt-2); leave stage(kt+1)'s 4 loads in flight
    asm volatile("s_waitcnt vmcnt(4)" ::: "memory");
    asm volatile("s_barrier" ::: "memory");
    if (kt + 2 < NK) stage((kt + 2) & 3, (kt + 2) * 32);
    bf16x8 a[4], b[4];
#pragma unroll
    for (int i = 0; i < 4; ++i) {
      a[i] = *(const bf16x8*)&smem[cur][(wm + i * 16 + lo) * 32 + kg];
      b[i] = *(const bf16x8*)&smem[cur][4096 + (wn + i * 16 + lo) * 32 + kg];
    }
    __builtin_amdgcn_s_setprio(1);
#pragma unroll
    for (int i = 0; i < 4; ++i)
#pragma unroll
      for (int j = 0; j < 4; ++j)
        acc[i][j] = __builtin_amdgcn_mfma_f32_16x16x32_bf16(a[i], b[j], acc[i][j], 0, 0, 0);
    __builtin_amdgcn_s_setprio(0);
  }
  {  // peeled last iteration
    const int cur = (NK - 1) & 3;
    asm volatile("s_waitcnt vmcnt(0)" ::: "memory");
    asm volatile("s_barrier" ::: "memory");
    bf16x8 a[4], b[4];
#pragma unroll
    for (int i = 0; i < 4; ++i) {
      a[i] = *(const bf16x8*)&smem[cur][(wm + i * 16 + lo) * 32 + kg];
      b[i] = *(const bf16x8*)&smem[cur][4096 + (wn + i * 16 + lo) * 32 + kg];
    }
#pragma unroll
    for (int i = 0; i < 4; ++i)
#pragma unroll
      for (int j = 0; j < 4; ++j)
        acc[i][j] = __builtin_amdgcn_mfma_f32_16x16x32_bf16(a[i], b[j], acc[i][j], 0, 0, 0);
  }

  const int rbase = m0 + wm + (hi << 2);
  const int cbase = n0 + wn + lo;

  if (SHARP) {
    __syncthreads();  // all waves done reading smem before epilogue reuse
    float rs[4][4];
#pragma unroll
    for (int i = 0; i < 4; ++i)
#pragma unroll
      for (int j = 0; j < 4; ++j) rs[i][j] = 0.f;
    unsigned short* ep = &smem[0][0];  // 32 KB tile: [128][128] u16
#pragma unroll
    for (int mi = 0; mi < 4; ++mi)
#pragma unroll
      for (int ni = 0; ni < 4; ++ni)
#pragma unroll
        for (int j = 0; j < 4; ++j) {
          float x = acc[mi][ni][j];
          float s = 1.f / (1.f + __expf(5.f - 10.f * x)) +
                    1.f / (1.f + __expf(5.f + 10.f * x));
          rs[mi][j] += s;
          int r = wm + mi * 16 + (hi << 2) + j;
          int c = wn + ni * 16 + lo;
          ep[r * 128 + c] = f2bf(s);
        }
#pragma unroll
    for (int mi = 0; mi < 4; ++mi)
#pragma unroll
      for (int j = 0; j < 4; ++j) {
        float v = rs[mi][j];
        v += __shfl_xor(v, 1);
        v += __shfl_xor(v, 2);
        v += __shfl_xor(v, 4);
        v += __shfl_xor(v, 8);
        if (lo == 0) atomicAdd(&rsum[rbase + mi * 16 + j], v);
      }
    __syncthreads();
    // coalesced 16B/lane store of the 128x128 tile
#pragma unroll
    for (int pass = 0; pass < 8; ++pass) {
      int idx = pass * 2048 + t * 8;
      int row = idx >> 7, col = idx & 127;
      ushort8 v = *(const ushort8*)&ep[idx];
      *(ushort8*)&wout[(size_t)(m0 + row) * C_DIM + n0 + col] = v;
    }
  } else {
    float rinv[4][4];
#pragma unroll
    for (int mi = 0; mi < 4; ++mi)
#pragma unroll
      for (int j = 0; j < 4; ++j)
        rinv[mi][j] = 1.f / rsum[rbase + mi * 16 + j];
#pragma unroll
    for (int mi = 0; mi < 4; ++mi)
#pragma unroll
      for (int ni = 0; ni < 4; ++ni)
#pragma unroll
        for (int j = 0; j < 4; ++j)
          fout[(size_t)(rbase + mi * 16 + j) * C_DIM + cbase + ni * 16] =
              acc[mi][ni][j] * rinv[mi][j];
  }
}

extern "C" void kernel_launch(void* const* d_in, const int* in_sizes, int n_in,
                              void* d_out, int out_size, void* d_ws, size_t ws_size,
                              hipStream_t stream) {
  const float* query = (const float*)d_in[0];
  const float* key = (const float*)d_in[1];
  const float* val = (const float*)d_in[2];
  float* out = (float*)d_out;
  const int B = in_sizes[0] / D_DIM;  // 65536

  char* ws = (char*)d_ws;
  unsigned short* kb = (unsigned short*)(ws);                         // 1 MB
  unsigned short* vbT = (unsigned short*)(ws + (1ull << 20));         // 2 MB
  float* rsum = (float*)(ws + 3ull * (1ull << 20));                   // 256 KB
  unsigned short* qb = (unsigned short*)(ws + 4ull * (1ull << 20));   // 64 MB
  unsigned short* wbf = (unsigned short*)(ws + 68ull * (1ull << 20)); // 128 MB

  rownorm_kernel<<<dim3(B / 4), dim3(256), 0, stream>>>(query, qb);
  rownorm_kernel<<<dim3(C_DIM / 4), dim3(256), 0, stream>>>(key, kb);
  valT_kernel<<<dim3(1024), dim3(256), 0, stream>>>(val, vbT);
  hipMemsetAsync(rsum, 0, (size_t)B * sizeof(float), stream);

  dim3 grid((B / 128) * (C_DIM / 128));
  gemm_kernel<D_DIM, true><<<grid, dim3(256), 0, stream>>>(qb, kb, wbf, rsum, nullptr);
  gemm_kernel<C_DIM, false><<<grid, dim3(256), 0, stream>>>(wbf, vbT, nullptr, rsum, out);
}

// Round 5
// 381.381 us; speedup vs baseline: 1.7784x; 1.1151x over previous
//
#include <hip/hip_runtime.h>
#include <hip/hip_bf16.h>

typedef __attribute__((ext_vector_type(8))) short bf16x8;
typedef __attribute__((ext_vector_type(8))) unsigned short ushort8;
typedef __attribute__((ext_vector_type(4))) float f32x4;
typedef unsigned int u32;

#define D_DIM 512
#define C_DIM 1024

__device__ __forceinline__ unsigned short f2bf(float x) {
  u32 u = __float_as_uint(x);
  u32 r = (u + 0x7fffu + ((u >> 16) & 1u)) >> 16;
  return (unsigned short)r;
}

__device__ __forceinline__ void async16(const void* g, void* l) {
  __builtin_amdgcn_global_load_lds(
      (const __attribute__((address_space(1))) u32*)g,
      (__attribute__((address_space(3))) u32*)l, 16, 0, 0);
}

// Normalize rows of length 512 (l2, +1e-12 eps) and cast to bf16.
__global__ __launch_bounds__(256) void rownorm_kernel(
    const float* __restrict__ src, unsigned short* __restrict__ dst) {
  int row = blockIdx.x * 4 + (threadIdx.x >> 6);
  int lane = threadIdx.x & 63;
  const float* s = src + (size_t)row * D_DIM + lane * 8;
  float4 v0 = *(const float4*)s;
  float4 v1 = *(const float4*)(s + 4);
  float ss = v0.x * v0.x + v0.y * v0.y + v0.z * v0.z + v0.w * v0.w +
             v1.x * v1.x + v1.y * v1.y + v1.z * v1.z + v1.w * v1.w;
#pragma unroll
  for (int m = 32; m >= 1; m >>= 1) ss += __shfl_xor(ss, m);
  float rinv = rsqrtf(ss + 1e-12f);
  float tv[8] = {v0.x, v0.y, v0.z, v0.w, v1.x, v1.y, v1.z, v1.w};
  ushort8 o;
#pragma unroll
  for (int i = 0; i < 8; ++i) o[i] = f2bf(tv[i] * rinv);
  *(ushort8*)(dst + (size_t)row * D_DIM + lane * 8) = o;
}

// vbT[n][k] = bf16(val[k][n])  (transpose+cast, 32x32 LDS tiles)
__global__ __launch_bounds__(256) void valT_kernel(
    const float* __restrict__ val, unsigned short* __restrict__ vbT) {
  __shared__ float tile[32][33];
  int bx = blockIdx.x & 31;  // n tile
  int by = blockIdx.x >> 5;  // k tile
  int t = threadIdx.x;
  int r = t >> 5, c = t & 31;
#pragma unroll
  for (int i = 0; i < 4; ++i)
    tile[r + i * 8][c] = val[(size_t)(by * 32 + r + i * 8) * C_DIM + bx * 32 + c];
  __syncthreads();
#pragma unroll
  for (int i = 0; i < 4; ++i)
    vbT[(size_t)(bx * 32 + r + i * 8) * C_DIM + by * 32 + c] = f2bf(tile[c][r + i * 8]);
}

// 8-phase 256x256 GEMM (m201 template, plain HIP). C = A(MxK)*B^T(NxK), bf16.
// 512 thr = 8 waves (2M x 4N); per-wave out 128x64 (8 mf x 4 nf 16x16 frags).
// BK=64; LDS = 2 dbuf x (A 32KB + B 32KB) = 128 KB, rows of 128B, XOR-swizzled
// (c ^= (r&7)<<4 bytes) via inverse-swizzled GLOBAL source + linear gload_lds
// dest + swizzled ds_read (both-sides rule).
// Stage unit k of K-tile T = A rows [k*32,k*32+32)u[128+k*32,..) + same B rows
// (16 KB, 2 gload_lds/thread). Schedule per K-tile T (4 phases):
//   ph0: ds_read A(mf 0,1) + ALL B (12 reads); stage(T+1, unit3); bar; 16 MFMA; bar
//   ph p=1..3: ds_read A(mf 2p,2p+1); stage(T+2, unit p-1); bar; 16 MFMA; bar
// Region safety: unit p-1 of buf[T&1] overwrites A rows read in phase p-1
// (done at its end-barrier) and B rows read in ph0; stage(T+1,3) targets the
// other buffer, whose readers finished at K-tile T-1's last barrier.
// K-tile head: s_waitcnt vmcnt(6) (=3 units in flight; retires this tile's
// last unit), vmcnt(0) at the final tile; then s_barrier. Prologue stages 7
// units. MFMA under setprio(1) (T5).
template <int K, bool SHARP>
__global__ __launch_bounds__(512, 2) void gemm256_kernel(
    const unsigned short* __restrict__ A, const unsigned short* __restrict__ Bm,
    unsigned short* __restrict__ wout, float* __restrict__ rsum,
    float* __restrict__ fout) {
  __shared__ unsigned short smem[65536];  // 128 KB
  const int NKT = K / 64;
  const int bid = blockIdx.x;
  // XCD-chunked bijective swizzle: nwg=1024, 8 XCDs, 128 per chunk.
  const int wg = (bid & 7) * 128 + (bid >> 3);
  const int m0 = (wg >> 2) * 256;  // 256 m-tiles
  const int n0 = (wg & 3) * 256;   // 4 n-tiles
  const int t = threadIdx.x;
  const int lane = t & 63;
  const int wv = t >> 6;
  const int wr = wv >> 2;  // 0..1
  const int wc = wv & 3;   // 0..3
  const int lo = lane & 15, hi = lane >> 4;
  const int swu = (lo & 7) << 3;  // read-side XOR swizzle (u16 units)

  // stage geometry: thread t covers 16B slot (t&7) of row (t>>3) of the unit
  const int s_ridx = t >> 3;     // 0..63
  const int s_c = (t & 7) * 8;   // phys col, u16
  auto stage = [&](int T, int k) {
    int r = (s_ridx < 32) ? (k * 32 + s_ridx) : (96 + k * 32 + s_ridx);
    int cl = s_c ^ ((r & 7) << 3);           // inverse-swizzled logical col
    size_t go = (size_t)T * 64 + cl;         // u16 offset in K
    int d = (T & 1) * 32768;
    async16(A + (size_t)(m0 + r) * K + go, &smem[d + r * 64 + s_c]);
    async16(Bm + (size_t)(n0 + r) * K + go, &smem[d + 16384 + r * 64 + s_c]);
  };

  f32x4 acc[8][4];
#pragma unroll
  for (int i = 0; i < 8; ++i)
#pragma unroll
    for (int j = 0; j < 4; ++j) acc[i][j] = (f32x4){0.f, 0.f, 0.f, 0.f};

  // prologue: K-tile 0 fully + 3 units of K-tile 1  (14 loads)
  stage(0, 0); stage(0, 1); stage(0, 2); stage(0, 3);
  stage(1, 0); stage(1, 1); stage(1, 2);

#pragma unroll 1
  for (int T = 0; T < NKT; ++T) {
    if (T == NKT - 1) {
      asm volatile("s_waitcnt vmcnt(0)" ::: "memory");
    } else {
      asm volatile("s_waitcnt vmcnt(6)" ::: "memory");
    }
    __builtin_amdgcn_s_barrier();
    const int d = (T & 1) * 32768;
    bf16x8 bfr[4][2];
#pragma unroll
    for (int p = 0; p < 4; ++p) {
      bf16x8 af[2][2];
#pragma unroll
      for (int mi = 0; mi < 2; ++mi)
#pragma unroll
        for (int ks = 0; ks < 2; ++ks) {
          int r = wr * 128 + (p * 2 + mi) * 16 + lo;
          af[mi][ks] = *(const bf16x8*)&smem[d + r * 64 + ((ks * 32 + hi * 8) ^ swu)];
        }
      if (p == 0) {
#pragma unroll
        for (int nf = 0; nf < 4; ++nf)
#pragma unroll
          for (int ks = 0; ks < 2; ++ks) {
            int r = wc * 64 + nf * 16 + lo;
            bfr[nf][ks] =
                *(const bf16x8*)&smem[d + 16384 + r * 64 + ((ks * 32 + hi * 8) ^ swu)];
          }
        if (T + 1 < NKT) stage(T + 1, 3);
      } else {
        if (T + 2 < NKT) stage(T + 2, p - 1);
      }
      __builtin_amdgcn_s_barrier();
      __builtin_amdgcn_s_setprio(1);
#pragma unroll
      for (int mi = 0; mi < 2; ++mi)
#pragma unroll
        for (int nf = 0; nf < 4; ++nf)
#pragma unroll
          for (int ks = 0; ks < 2; ++ks)
            acc[p * 2 + mi][nf] = __builtin_amdgcn_mfma_f32_16x16x32_bf16(
                af[mi][ks], bfr[nf][ks], acc[p * 2 + mi][nf], 0, 0, 0);
      __builtin_amdgcn_s_setprio(0);
      __builtin_amdgcn_s_barrier();
    }
  }
  __syncthreads();  // K-loop fully drained (vmcnt 0 since last head); reuse LDS

  if (SHARP) {
    float rs[8][4];
#pragma unroll
    for (int i = 0; i < 8; ++i)
#pragma unroll
      for (int j = 0; j < 4; ++j) rs[i][j] = 0.f;
    unsigned short* ep = smem;  // 256x256 u16 = 128 KB
#pragma unroll
    for (int mf = 0; mf < 8; ++mf)
#pragma unroll
      for (int nf = 0; nf < 4; ++nf)
#pragma unroll
        for (int j = 0; j < 4; ++j) {
          float x = acc[mf][nf][j];
          float s = 1.f / (1.f + __expf(5.f - 10.f * x)) +
                    1.f / (1.f + __expf(5.f + 10.f * x));
          rs[mf][j] += s;
          int rl = wr * 128 + mf * 16 + (hi << 2) + j;
          int cl = wc * 64 + nf * 16 + lo;
          ep[rl * 256 + cl] = f2bf(s);
        }
#pragma unroll
    for (int mf = 0; mf < 8; ++mf)
#pragma unroll
      for (int j = 0; j < 4; ++j) {
        float v = rs[mf][j];
        v += __shfl_xor(v, 1);
        v += __shfl_xor(v, 2);
        v += __shfl_xor(v, 4);
        v += __shfl_xor(v, 8);
        if (lo == 0)
          atomicAdd(&rsum[m0 + wr * 128 + mf * 16 + (hi << 2) + j], v);
      }
    __syncthreads();
    // coalesced 16B/lane store of the 256x256 tile
#pragma unroll
    for (int pass = 0; pass < 16; ++pass) {
      int idx = pass * 4096 + t * 8;
      int row = idx >> 8, col = idx & 255;
      *(ushort8*)&wout[(size_t)(m0 + row) * C_DIM + n0 + col] = *(const ushort8*)&ep[idx];
    }
  } else {
    float rinv[8][4];
#pragma unroll
    for (int mf = 0; mf < 8; ++mf)
#pragma unroll
      for (int j = 0; j < 4; ++j)
        rinv[mf][j] = 1.f / rsum[m0 + wr * 128 + mf * 16 + (hi << 2) + j];
#pragma unroll
    for (int mf = 0; mf < 8; ++mf)
#pragma unroll
      for (int nf = 0; nf < 4; ++nf)
#pragma unroll
        for (int j = 0; j < 4; ++j)
          fout[(size_t)(m0 + wr * 128 + mf * 16 + (hi << 2) + j) * C_DIM +
               n0 + wc * 64 + nf * 16 + lo] = acc[mf][nf][j] * rinv[mf][j];
  }
}

extern "C" void kernel_launch(void* const* d_in, const int* in_sizes, int n_in,
                              void* d_out, int out_size, void* d_ws, size_t ws_size,
                              hipStream_t stream) {
  const float* query = (const float*)d_in[0];
  const float* key = (const float*)d_in[1];
  const float* val = (const float*)d_in[2];
  float* out = (float*)d_out;
  const int B = in_sizes[0] / D_DIM;  // 65536

  char* ws = (char*)d_ws;
  unsigned short* kb = (unsigned short*)(ws);                         // 1 MB
  unsigned short* vbT = (unsigned short*)(ws + (1ull << 20));         // 2 MB
  float* rsum = (float*)(ws + 3ull * (1ull << 20));                   // 256 KB
  unsigned short* qb = (unsigned short*)(ws + 4ull * (1ull << 20));   // 64 MB
  unsigned short* wbf = (unsigned short*)(ws + 68ull * (1ull << 20)); // 128 MB

  rownorm_kernel<<<dim3(B / 4), dim3(256), 0, stream>>>(query, qb);
  rownorm_kernel<<<dim3(C_DIM / 4), dim3(256), 0, stream>>>(key, kb);
  valT_kernel<<<dim3(1024), dim3(256), 0, stream>>>(val, vbT);
  hipMemsetAsync(rsum, 0, (size_t)B * sizeof(float), stream);

  dim3 grid((B / 256) * (C_DIM / 256));  // 1024 blocks
  gemm256_kernel<D_DIM, true><<<grid, dim3(512), 0, stream>>>(qb, kb, wbf, rsum, nullptr);
  gemm256_kernel<C_DIM, false><<<grid, dim3(512), 0, stream>>>(wbf, vbT, nullptr, rsum, out);
}

// Round 6
// 359.632 us; speedup vs baseline: 1.8860x; 1.0605x over previous
//
#include <hip/hip_runtime.h>
#include <hip/hip_bf16.h>

typedef __attribute__((ext_vector_type(8))) short bf16x8;
typedef __attribute__((ext_vector_type(8))) unsigned short ushort8;
typedef __attribute__((ext_vector_type(4))) float f32x4;
typedef unsigned int u32;

#define D_DIM 512
#define C_DIM 1024

__device__ __forceinline__ unsigned short f2bf(float x) {
  u32 u = __float_as_uint(x);
  u32 r = (u + 0x7fffu + ((u >> 16) & 1u)) >> 16;
  return (unsigned short)r;
}

__device__ __forceinline__ void async16(const void* g, void* l) {
  __builtin_amdgcn_global_load_lds(
      (const __attribute__((address_space(1))) u32*)g,
      (__attribute__((address_space(3))) u32*)l, 16, 0, 0);
}

// sharp(x) = sigmoid(10x-5) + sigmoid(-10x-5), x in [-1,1].
// = t/(1+t) + 1/(1+t*e^10) with t = e^(10x-5). 1 exp + 2 hw rcp.
__device__ __forceinline__ float sharpf(float x) {
  float t = __expf(10.f * x - 5.f);
  return t * __builtin_amdgcn_rcpf(1.f + t) +
         __builtin_amdgcn_rcpf(1.f + t * 22026.4658f);
}

// Normalize rows of length 512 (l2, +1e-12 eps) and cast to bf16.
__global__ __launch_bounds__(256) void rownorm_kernel(
    const float* __restrict__ src, unsigned short* __restrict__ dst) {
  int row = blockIdx.x * 4 + (threadIdx.x >> 6);
  int lane = threadIdx.x & 63;
  const float* s = src + (size_t)row * D_DIM + lane * 8;
  float4 v0 = *(const float4*)s;
  float4 v1 = *(const float4*)(s + 4);
  float ss = v0.x * v0.x + v0.y * v0.y + v0.z * v0.z + v0.w * v0.w +
             v1.x * v1.x + v1.y * v1.y + v1.z * v1.z + v1.w * v1.w;
#pragma unroll
  for (int m = 32; m >= 1; m >>= 1) ss += __shfl_xor(ss, m);
  float rinv = rsqrtf(ss + 1e-12f);
  float tv[8] = {v0.x, v0.y, v0.z, v0.w, v1.x, v1.y, v1.z, v1.w};
  ushort8 o;
#pragma unroll
  for (int i = 0; i < 8; ++i) o[i] = f2bf(tv[i] * rinv);
  *(ushort8*)(dst + (size_t)row * D_DIM + lane * 8) = o;
}

// vbT[n][k] = bf16(val[k][n])  (transpose+cast, 32x32 LDS tiles)
__global__ __launch_bounds__(256) void valT_kernel(
    const float* __restrict__ val, unsigned short* __restrict__ vbT) {
  __shared__ float tile[32][33];
  int bx = blockIdx.x & 31;  // n tile
  int by = blockIdx.x >> 5;  // k tile
  int t = threadIdx.x;
  int r = t >> 5, c = t & 31;
#pragma unroll
  for (int i = 0; i < 4; ++i)
    tile[r + i * 8][c] = val[(size_t)(by * 32 + r + i * 8) * C_DIM + bx * 32 + c];
  __syncthreads();
#pragma unroll
  for (int i = 0; i < 4; ++i)
    vbT[(size_t)(bx * 32 + r + i * 8) * C_DIM + by * 32 + c] = f2bf(tile[c][r + i * 8]);
}

// 256x256 GEMM, BK=64, 8 waves (2Mx4N), per-wave 128x64. Single barrier per
// phase: [reads(p) | BAR | stage | MFMA]. 4 barriers/K-tile (was 8).
// Race ledger: stage(T+2,p-1) issued after BAR(p); unit p-1's readers retired
// (lgkm before MFMA p-1) before BAR(p). reads(p) precede BAR(p); unit p's
// only overwriter is stage(T+2,p), issued after BAR(p+1). stage(T+1,3) after
// head-BAR(T); its unit's readers retired before MFMA p3(T-1) < head-BAR(T).
// vmcnt: head waits vmcnt(6) (3 units in flight), final tile vmcnt(0); the
// barrier after the wait makes each wave's landed-units globally visible.
template <int K, bool SHARP>
__global__ __launch_bounds__(512, 2) void gemm256_kernel(
    const unsigned short* __restrict__ A, const unsigned short* __restrict__ Bm,
    unsigned short* __restrict__ wout, float* __restrict__ rsum,
    float* __restrict__ fout) {
  __shared__ unsigned short smem[65536];  // 128 KB
  const int NKT = K / 64;
  const int bid = blockIdx.x;
  // XCD-chunked bijective swizzle: nwg=1024, 8 XCDs, 128 per chunk.
  const int wg = (bid & 7) * 128 + (bid >> 3);
  const int m0 = (wg >> 2) * 256;
  const int n0 = (wg & 3) * 256;
  const int t = threadIdx.x;
  const int lane = t & 63;
  const int wv = t >> 6;
  const int wr = wv >> 2;  // 0..1
  const int wc = wv & 3;   // 0..3
  const int lo = lane & 15, hi = lane >> 4;
  const int swu = (lo & 7) << 3;  // read-side XOR swizzle (u16 units)

  const int s_ridx = t >> 3;    // 0..63
  const int s_c = (t & 7) * 8;  // phys col, u16
  auto stage = [&](int T, int k) {
    int r = (s_ridx < 32) ? (k * 32 + s_ridx) : (96 + k * 32 + s_ridx);
    int cl = s_c ^ ((r & 7) << 3);  // inverse-swizzled logical col
    size_t go = (size_t)T * 64 + cl;
    int d = (T & 1) * 32768;
    async16(A + (size_t)(m0 + r) * K + go, &smem[d + r * 64 + s_c]);
    async16(Bm + (size_t)(n0 + r) * K + go, &smem[d + 16384 + r * 64 + s_c]);
  };

  f32x4 acc[8][4];
#pragma unroll
  for (int i = 0; i < 8; ++i)
#pragma unroll
    for (int j = 0; j < 4; ++j) acc[i][j] = (f32x4){0.f, 0.f, 0.f, 0.f};

  // prologue: K-tile 0 fully + 3 units of K-tile 1  (14 loads in flight)
  stage(0, 0); stage(0, 1); stage(0, 2); stage(0, 3);
  stage(1, 0); stage(1, 1); stage(1, 2);

#pragma unroll 1
  for (int T = 0; T < NKT; ++T) {
    if (T == NKT - 1) {
      asm volatile("s_waitcnt vmcnt(0)" ::: "memory");
    } else {
      asm volatile("s_waitcnt vmcnt(6)" ::: "memory");
    }
    __builtin_amdgcn_s_barrier();
    const int d = (T & 1) * 32768;
    bf16x8 bfr[4][2];
    {  // phase 0: af(mf0,1) + all B; stage(T+1, unit3); MFMA quadrant 0
      bf16x8 af[2][2];
#pragma unroll
      for (int mi = 0; mi < 2; ++mi)
#pragma unroll
        for (int ks = 0; ks < 2; ++ks) {
          int r = wr * 128 + mi * 16 + lo;
          af[mi][ks] = *(const bf16x8*)&smem[d + r * 64 + ((ks * 32 + hi * 8) ^ swu)];
        }
#pragma unroll
      for (int nf = 0; nf < 4; ++nf)
#pragma unroll
        for (int ks = 0; ks < 2; ++ks) {
          int r = wc * 64 + nf * 16 + lo;
          bfr[nf][ks] =
              *(const bf16x8*)&smem[d + 16384 + r * 64 + ((ks * 32 + hi * 8) ^ swu)];
        }
      if (T + 1 < NKT) stage(T + 1, 3);
      __builtin_amdgcn_s_setprio(1);
#pragma unroll
      for (int mi = 0; mi < 2; ++mi)
#pragma unroll
        for (int nf = 0; nf < 4; ++nf)
#pragma unroll
          for (int ks = 0; ks < 2; ++ks)
            acc[mi][nf] = __builtin_amdgcn_mfma_f32_16x16x32_bf16(
                af[mi][ks], bfr[nf][ks], acc[mi][nf], 0, 0, 0);
      __builtin_amdgcn_s_setprio(0);
    }
#pragma unroll
    for (int p = 1; p < 4; ++p) {  // phases 1..3
      bf16x8 af[2][2];
#pragma unroll
      for (int mi = 0; mi < 2; ++mi)
#pragma unroll
        for (int ks = 0; ks < 2; ++ks) {
          int r = wr * 128 + (p * 2 + mi) * 16 + lo;
          af[mi][ks] = *(const bf16x8*)&smem[d + r * 64 + ((ks * 32 + hi * 8) ^ swu)];
        }
      __builtin_amdgcn_s_barrier();
      if (T + 2 < NKT) stage(T + 2, p - 1);
      __builtin_amdgcn_s_setprio(1);
#pragma unroll
      for (int mi = 0; mi < 2; ++mi)
#pragma unroll
        for (int nf = 0; nf < 4; ++nf)
#pragma unroll
          for (int ks = 0; ks < 2; ++ks)
            acc[p * 2 + mi][nf] = __builtin_amdgcn_mfma_f32_16x16x32_bf16(
                af[mi][ks], bfr[nf][ks], acc[p * 2 + mi][nf], 0, 0, 0);
      __builtin_amdgcn_s_setprio(0);
    }
  }
  __syncthreads();  // K-loop drained (vmcnt 0 at last head); reuse LDS

  if (SHARP) {
    float rs[8][4];
#pragma unroll
    for (int i = 0; i < 8; ++i)
#pragma unroll
      for (int j = 0; j < 4; ++j) rs[i][j] = 0.f;
    unsigned short* ep = smem;  // 256x256 u16 = 128 KB
#pragma unroll
    for (int mf = 0; mf < 8; ++mf)
#pragma unroll
      for (int nf = 0; nf < 4; ++nf)
#pragma unroll
        for (int j = 0; j < 4; ++j) {
          float s = sharpf(acc[mf][nf][j]);
          rs[mf][j] += s;
          int rl = wr * 128 + mf * 16 + (hi << 2) + j;
          int cl = wc * 64 + nf * 16 + lo;
          ep[rl * 256 + cl] = f2bf(s);
        }
#pragma unroll
    for (int mf = 0; mf < 8; ++mf)
#pragma unroll
      for (int j = 0; j < 4; ++j) {
        float v = rs[mf][j];
        v += __shfl_xor(v, 1);
        v += __shfl_xor(v, 2);
        v += __shfl_xor(v, 4);
        v += __shfl_xor(v, 8);
        if (lo == 0)
          atomicAdd(&rsum[m0 + wr * 128 + mf * 16 + (hi << 2) + j], v);
      }
    __syncthreads();
#pragma unroll
    for (int pass = 0; pass < 16; ++pass) {
      int idx = pass * 4096 + t * 8;
      int row = idx >> 8, col = idx & 255;
      *(ushort8*)&wout[(size_t)(m0 + row) * C_DIM + n0 + col] = *(const ushort8*)&ep[idx];
    }
  } else {
    float rinv[8][4];
#pragma unroll
    for (int mf = 0; mf < 8; ++mf)
#pragma unroll
      for (int j = 0; j < 4; ++j)
        rinv[mf][j] =
            __builtin_amdgcn_rcpf(rsum[m0 + wr * 128 + mf * 16 + (hi << 2) + j]);
#pragma unroll
    for (int mf = 0; mf < 8; ++mf)
#pragma unroll
      for (int nf = 0; nf < 4; ++nf)
#pragma unroll
        for (int j = 0; j < 4; ++j)
          fout[(size_t)(m0 + wr * 128 + mf * 16 + (hi << 2) + j) * C_DIM +
               n0 + wc * 64 + nf * 16 + lo] = acc[mf][nf][j] * rinv[mf][j];
  }
}

extern "C" void kernel_launch(void* const* d_in, const int* in_sizes, int n_in,
                              void* d_out, int out_size, void* d_ws, size_t ws_size,
                              hipStream_t stream) {
  const float* query = (const float*)d_in[0];
  const float* key = (const float*)d_in[1];
  const float* val = (const float*)d_in[2];
  float* out = (float*)d_out;
  const int B = in_sizes[0] / D_DIM;  // 65536

  char* ws = (char*)d_ws;
  unsigned short* kb = (unsigned short*)(ws);                         // 1 MB
  unsigned short* vbT = (unsigned short*)(ws + (1ull << 20));         // 2 MB
  float* rsum = (float*)(ws + 3ull * (1ull << 20));                   // 256 KB
  unsigned short* qb = (unsigned short*)(ws + 4ull * (1ull << 20));   // 64 MB
  unsigned short* wbf = (unsigned short*)(ws + 68ull * (1ull << 20)); // 128 MB

  rownorm_kernel<<<dim3(B / 4), dim3(256), 0, stream>>>(query, qb);
  rownorm_kernel<<<dim3(C_DIM / 4), dim3(256), 0, stream>>>(key, kb);
  valT_kernel<<<dim3(1024), dim3(256), 0, stream>>>(val, vbT);
  hipMemsetAsync(rsum, 0, (size_t)B * sizeof(float), stream);

  dim3 grid((B / 256) * (C_DIM / 256));  // 1024 blocks
  gemm256_kernel<D_DIM, true><<<grid, dim3(512), 0, stream>>>(qb, kb, wbf, rsum, nullptr);
  gemm256_kernel<C_DIM, false><<<grid, dim3(512), 0, stream>>>(wbf, vbT, nullptr, rsum, out);
}

// Round 7
// 326.080 us; speedup vs baseline: 2.0800x; 1.1029x over previous
//
#include <hip/hip_runtime.h>
#include <hip/hip_bf16.h>

typedef __attribute__((ext_vector_type(8))) short bf16x8;
typedef __attribute__((ext_vector_type(8))) unsigned short ushort8;
typedef __attribute__((ext_vector_type(4))) float f32x4;
typedef unsigned int u32;

#define D_DIM 512
#define C_DIM 1024
#define B_DIM 65536

__device__ __forceinline__ unsigned short f2bf(float x) {
  u32 u = __float_as_uint(x);
  u32 r = (u + 0x7fffu + ((u >> 16) & 1u)) >> 16;
  return (unsigned short)r;
}

__device__ __forceinline__ void async16(const void* g, void* l) {
  __builtin_amdgcn_global_load_lds(
      (const __attribute__((address_space(1))) u32*)g,
      (__attribute__((address_space(3))) u32*)l, 16, 0, 0);
}

// sharp(x) = sigmoid(10x-5) + sigmoid(-10x-5)
//          = (E t^2 + 2t + 1) / (E t^2 + (1+E) t + 1),  t = e^(10x-5), E = e^10.
// 1 exp + 1 rcp + 4 fma.  |x|<=1.01 -> t<=161, E t^2 <= 5.7e8 (f32-safe).
__device__ __forceinline__ float sharpf(float x) {
  float t = __expf(10.f * x - 5.f);
  float u = 22026.4658f * t * t;
  float num = u + 2.f * t + 1.f;
  float den = u + 22027.4658f * t + 1.f;
  return num * __builtin_amdgcn_rcpf(den);
}

// Normalize rows of length 512 (l2, +1e-12 eps) and cast to bf16.
__global__ __launch_bounds__(256) void rownorm_kernel(
    const float* __restrict__ src, unsigned short* __restrict__ dst) {
  int row = blockIdx.x * 4 + (threadIdx.x >> 6);
  int lane = threadIdx.x & 63;
  const float* s = src + (size_t)row * D_DIM + lane * 8;
  float4 v0 = *(const float4*)s;
  float4 v1 = *(const float4*)(s + 4);
  float ss = v0.x * v0.x + v0.y * v0.y + v0.z * v0.z + v0.w * v0.w +
             v1.x * v1.x + v1.y * v1.y + v1.z * v1.z + v1.w * v1.w;
#pragma unroll
  for (int m = 32; m >= 1; m >>= 1) ss += __shfl_xor(ss, m);
  float rinv = rsqrtf(ss + 1e-12f);
  float tv[8] = {v0.x, v0.y, v0.z, v0.w, v1.x, v1.y, v1.z, v1.w};
  ushort8 o;
#pragma unroll
  for (int i = 0; i < 8; ++i) o[i] = f2bf(tv[i] * rinv);
  *(ushort8*)(dst + (size_t)row * D_DIM + lane * 8) = o;
}

// vbT[n][k] = bf16(val[k][n])  (transpose+cast, 32x32 LDS tiles)
__global__ __launch_bounds__(256) void valT_kernel(
    const float* __restrict__ val, unsigned short* __restrict__ vbT) {
  __shared__ float tile[32][33];
  int bx = blockIdx.x & 31;  // n tile
  int by = blockIdx.x >> 5;  // k tile
  int t = threadIdx.x;
  int r = t >> 5, c = t & 31;
#pragma unroll
  for (int i = 0; i < 4; ++i)
    tile[r + i * 8][c] = val[(size_t)(by * 32 + r + i * 8) * C_DIM + bx * 32 + c];
  __syncthreads();
#pragma unroll
  for (int i = 0; i < 4; ++i)
    vbT[(size_t)(bx * 32 + r + i * 8) * C_DIM + by * 32 + c] = f2bf(tile[c][r + i * 8]);
}

// rsum[i] = sum of the 4 per-n-block partials
__global__ __launch_bounds__(256) void rsum_reduce_kernel(
    const float* __restrict__ part, float* __restrict__ rsum) {
  int i = blockIdx.x * 256 + threadIdx.x;
  rsum[i] = (part[i] + part[i + B_DIM]) +
            (part[i + 2 * B_DIM] + part[i + 3 * B_DIM]);
}

// 256x256 GEMM, BK=64, 8 waves (2Mx4N), per-wave 128x64. Single barrier per
// phase: [reads(p) | BAR | stage | MFMA]. Race ledger: stage(T+2,p-1) issued
// after BAR(p); unit p-1's readers retired (lgkm before MFMA p-1) before
// BAR(p). reads(p) precede BAR(p); unit p's only overwriter is stage(T+2,p),
// issued after BAR(p+1). vmcnt: head waits vmcnt(6), final tile vmcnt(0).
// SHARP epilogue: sharp -> conflict-free swizzled LDS scatter (phys col ^=
// ((rl>>2)&3)<<4 => the 4 hi-row groups hit disjoint bank quartets) ->
// coalesced 16B w store -> LDS wc-reduce of row sums -> plain store to
// rsum_part[n][row] (no atomics).  !SHARP: scale by rcp(rsum[row]), f32 store.
template <int K, bool SHARP>
__global__ __launch_bounds__(512, 2) void gemm256_kernel(
    const unsigned short* __restrict__ A, const unsigned short* __restrict__ Bm,
    unsigned short* __restrict__ wout, float* __restrict__ rsum,
    float* __restrict__ fout) {
  __shared__ unsigned short smem[65536];  // 128 KB
  const int NKT = K / 64;
  const int bid = blockIdx.x;
  // XCD-chunked bijective swizzle: nwg=1024, 8 XCDs, 128 per chunk.
  const int wg = (bid & 7) * 128 + (bid >> 3);
  const int m0 = (wg >> 2) * 256;
  const int n0 = (wg & 3) * 256;
  const int t = threadIdx.x;
  const int lane = t & 63;
  const int wv = t >> 6;
  const int wr = wv >> 2;  // 0..1
  const int wc = wv & 3;   // 0..3
  const int lo = lane & 15, hi = lane >> 4;
  const int swu = (lo & 7) << 3;  // read-side XOR swizzle (u16 units)

  const int s_ridx = t >> 3;    // 0..63
  const int s_c = (t & 7) * 8;  // phys col, u16
  auto stage = [&](int T, int k) {
    int r = (s_ridx < 32) ? (k * 32 + s_ridx) : (96 + k * 32 + s_ridx);
    int cl = s_c ^ ((r & 7) << 3);  // inverse-swizzled logical col
    size_t go = (size_t)T * 64 + cl;
    int d = (T & 1) * 32768;
    async16(A + (size_t)(m0 + r) * K + go, &smem[d + r * 64 + s_c]);
    async16(Bm + (size_t)(n0 + r) * K + go, &smem[d + 16384 + r * 64 + s_c]);
  };

  f32x4 acc[8][4];
#pragma unroll
  for (int i = 0; i < 8; ++i)
#pragma unroll
    for (int j = 0; j < 4; ++j) acc[i][j] = (f32x4){0.f, 0.f, 0.f, 0.f};

  // prologue: K-tile 0 fully + 3 units of K-tile 1  (14 loads in flight)
  stage(0, 0); stage(0, 1); stage(0, 2); stage(0, 3);
  stage(1, 0); stage(1, 1); stage(1, 2);

#pragma unroll 1
  for (int T = 0; T < NKT; ++T) {
    if (T == NKT - 1) {
      asm volatile("s_waitcnt vmcnt(0)" ::: "memory");
    } else {
      asm volatile("s_waitcnt vmcnt(6)" ::: "memory");
    }
    __builtin_amdgcn_s_barrier();
    const int d = (T & 1) * 32768;
    bf16x8 bfr[4][2];
    {  // phase 0: af(mf0,1) + all B; stage(T+1, unit3); MFMA quadrant 0
      bf16x8 af[2][2];
#pragma unroll
      for (int mi = 0; mi < 2; ++mi)
#pragma unroll
        for (int ks = 0; ks < 2; ++ks) {
          int r = wr * 128 + mi * 16 + lo;
          af[mi][ks] = *(const bf16x8*)&smem[d + r * 64 + ((ks * 32 + hi * 8) ^ swu)];
        }
#pragma unroll
      for (int nf = 0; nf < 4; ++nf)
#pragma unroll
        for (int ks = 0; ks < 2; ++ks) {
          int r = wc * 64 + nf * 16 + lo;
          bfr[nf][ks] =
              *(const bf16x8*)&smem[d + 16384 + r * 64 + ((ks * 32 + hi * 8) ^ swu)];
        }
      if (T + 1 < NKT) stage(T + 1, 3);
      __builtin_amdgcn_s_setprio(1);
#pragma unroll
      for (int mi = 0; mi < 2; ++mi)
#pragma unroll
        for (int nf = 0; nf < 4; ++nf)
#pragma unroll
          for (int ks = 0; ks < 2; ++ks)
            acc[mi][nf] = __builtin_amdgcn_mfma_f32_16x16x32_bf16(
                af[mi][ks], bfr[nf][ks], acc[mi][nf], 0, 0, 0);
      __builtin_amdgcn_s_setprio(0);
    }
#pragma unroll
    for (int p = 1; p < 4; ++p) {  // phases 1..3
      bf16x8 af[2][2];
#pragma unroll
      for (int mi = 0; mi < 2; ++mi)
#pragma unroll
        for (int ks = 0; ks < 2; ++ks) {
          int r = wr * 128 + (p * 2 + mi) * 16 + lo;
          af[mi][ks] = *(const bf16x8*)&smem[d + r * 64 + ((ks * 32 + hi * 8) ^ swu)];
        }
      __builtin_amdgcn_s_barrier();
      if (T + 2 < NKT) stage(T + 2, p - 1);
      __builtin_amdgcn_s_setprio(1);
#pragma unroll
      for (int mi = 0; mi < 2; ++mi)
#pragma unroll
        for (int nf = 0; nf < 4; ++nf)
#pragma unroll
          for (int ks = 0; ks < 2; ++ks)
            acc[p * 2 + mi][nf] = __builtin_amdgcn_mfma_f32_16x16x32_bf16(
                af[mi][ks], bfr[nf][ks], acc[p * 2 + mi][nf], 0, 0, 0);
      __builtin_amdgcn_s_setprio(0);
    }
  }
  __syncthreads();  // K-loop drained (vmcnt 0 at last head); reuse LDS

  if (SHARP) {
    float rs[8][4];
#pragma unroll
    for (int i = 0; i < 8; ++i)
#pragma unroll
      for (int j = 0; j < 4; ++j) rs[i][j] = 0.f;
    unsigned short* ep = smem;  // 256x256 u16 = 128 KB
#pragma unroll
    for (int mf = 0; mf < 8; ++mf)
#pragma unroll
      for (int nf = 0; nf < 4; ++nf)
#pragma unroll
        for (int j = 0; j < 4; ++j) {
          float s = sharpf(acc[mf][nf][j]);
          rs[mf][j] += s;
          int rl = wr * 128 + mf * 16 + (hi << 2) + j;
          int cl = (wc * 64 + nf * 16 + lo) ^ (((rl >> 2) & 3) << 4);
          ep[rl * 256 + cl] = f2bf(s);
        }
    // reduce rs over the 16 lo-lanes (butterfly; all lanes end with the sum)
#pragma unroll
    for (int mf = 0; mf < 8; ++mf)
#pragma unroll
      for (int j = 0; j < 4; ++j) {
        float v = rs[mf][j];
        v += __shfl_xor(v, 1);
        v += __shfl_xor(v, 2);
        v += __shfl_xor(v, 4);
        v += __shfl_xor(v, 8);
        rs[mf][j] = v;
      }
    __syncthreads();
    // coalesced 16B/lane store of the 256x256 tile (un-swizzling on read)
#pragma unroll
    for (int pass = 0; pass < 16; ++pass) {
      int idx = pass * 4096 + t * 8;
      int row = idx >> 8, col = idx & 255;
      int phys = row * 256 + (col ^ (((row >> 2) & 3) << 4));
      *(ushort8*)&wout[(size_t)(m0 + row) * C_DIM + n0 + col] =
          *(const ushort8*)&ep[phys];
    }
    __syncthreads();
    // wc-reduction of row sums via 4 KB of LDS, then plain global store
    float* rbuf = (float*)smem;  // [4][256]
    if (lo == 0) {
#pragma unroll
      for (int mf = 0; mf < 8; ++mf)
#pragma unroll
        for (int j = 0; j < 4; ++j)
          rbuf[wc * 256 + wr * 128 + mf * 16 + (hi << 2) + j] = rs[mf][j];
    }
    __syncthreads();
    if (t < 256) {
      float v = (rbuf[t] + rbuf[256 + t]) + (rbuf[512 + t] + rbuf[768 + t]);
      rsum[(size_t)(wg & 3) * B_DIM + m0 + t] = v;  // rsum = rsum_part here
    }
  } else {
    float rinv[8][4];
#pragma unroll
    for (int mf = 0; mf < 8; ++mf)
#pragma unroll
      for (int j = 0; j < 4; ++j)
        rinv[mf][j] =
            __builtin_amdgcn_rcpf(rsum[m0 + wr * 128 + mf * 16 + (hi << 2) + j]);
#pragma unroll
    for (int mf = 0; mf < 8; ++mf)
#pragma unroll
      for (int nf = 0; nf < 4; ++nf)
#pragma unroll
        for (int j = 0; j < 4; ++j)
          fout[(size_t)(m0 + wr * 128 + mf * 16 + (hi << 2) + j) * C_DIM +
               n0 + wc * 64 + nf * 16 + lo] = acc[mf][nf][j] * rinv[mf][j];
  }
}

extern "C" void kernel_launch(void* const* d_in, const int* in_sizes, int n_in,
                              void* d_out, int out_size, void* d_ws, size_t ws_size,
                              hipStream_t stream) {
  const float* query = (const float*)d_in[0];
  const float* key = (const float*)d_in[1];
  const float* val = (const float*)d_in[2];
  float* out = (float*)d_out;
  const int B = in_sizes[0] / D_DIM;  // 65536

  char* ws = (char*)d_ws;
  unsigned short* kb = (unsigned short*)(ws);                         // 1 MB
  unsigned short* vbT = (unsigned short*)(ws + (1ull << 20));         // 2 MB
  float* rsum_part = (float*)(ws + 3ull * (1ull << 20));              // 1 MB
  unsigned short* qb = (unsigned short*)(ws + 4ull * (1ull << 20));   // 64 MB
  float* rsum = (float*)qb;  // reuses qb region (dead after GEMM1)
  unsigned short* wbf = (unsigned short*)(ws + 68ull * (1ull << 20)); // 128 MB

  rownorm_kernel<<<dim3(B / 4), dim3(256), 0, stream>>>(query, qb);
  rownorm_kernel<<<dim3(C_DIM / 4), dim3(256), 0, stream>>>(key, kb);
  valT_kernel<<<dim3(1024), dim3(256), 0, stream>>>(val, vbT);

  dim3 grid((B / 256) * (C_DIM / 256));  // 1024 blocks
  gemm256_kernel<D_DIM, true><<<grid, dim3(512), 0, stream>>>(qb, kb, wbf, rsum_part, nullptr);
  rsum_reduce_kernel<<<dim3(B / 256), dim3(256), 0, stream>>>(rsum_part, rsum);
  gemm256_kernel<C_DIM, false><<<grid, dim3(512), 0, stream>>>(wbf, vbT, nullptr, rsum, out);
}